// Round 13
// baseline (17.783 us; speedup 1.0000x reference)
//
#include <hip/hip_runtime.h>
#include <math.h>

// Realspace Ewald: pot = 2 * sum_{i<j} q_i q_j erf(d_ij/sqrt(2))/d_ij * NORM/(4pi)
// N=6144. erf via A&S 7.1.23 rational (absmax 0.0 since R6), Estrin, packed
// fp32 (2 i-particles per lane -> v_pk_*). R13: TRIANGLE-FOLDED BALANCED GRID:
// strip s pairs with strip 11-s -> constant 6656 j-columns per super-strip ->
// 6 supers x 256 chunks x 26 cols = 1536 blocks = exactly 6 blocks/CU, one
// generation, no ragged tail; closed-form bid->tile map; hot path = single
// compile-time-26 unrolled phase (only 6 fold-crossing blocks take 2 phases).

#if __has_builtin(__builtin_amdgcn_rsqf)
#define FRSQ(x) __builtin_amdgcn_rsqf(x)
#else
#define FRSQ(x) rsqrtf(x)
#endif
#if __has_builtin(__builtin_amdgcn_rcpf)
#define FRCP(x) __builtin_amdgcn_rcpf(x)
#else
#define FRCP(x) (1.0f / (x))
#endif

typedef float vf2 __attribute__((ext_vector_type(2)));

__device__ __forceinline__ vf2 vfma(vf2 a, vf2 b, vf2 c) {
  return __builtin_elementwise_fma(a, b, c);
}

// A&S 7.1.23 coefficients pre-multiplied by (1/sqrt(2))^k so poly is in d:
#define B1 0.19685360f
#define B2 0.11519450f
#define B3 0.00034366f
#define B4 0.01952700f

template <bool CHECK>
__device__ __forceinline__ void pair2_body(const float4 v, int jj, int i0,
                                           vf2 xi, vf2 yi, vf2 zi, vf2& acc) {
  vf2 dx = xi - v.x, dy = yi - v.y, dz = zi - v.z;
  vf2 s = vfma(dx, dx, vfma(dy, dy, dz * dz));
  vf2 qk = {v.w, v.w};
  if (CHECK) {
    bool t0 = (jj > i0);
    bool t1 = (jj > i0 + 64);
    s.x = t0 ? s.x : 1.0f;
    s.y = t1 ? s.y : 1.0f;
    qk.x = t0 ? qk.x : 0.0f;
    qk.y = t1 ? qk.y : 0.0f;
  }
  vf2 ri;
  ri.x = FRSQ(s.x);
  ri.y = FRSQ(s.y);
  // Estrin: poly = (1 + B2 s + B4 s^2) + d*(B1 + B3 s); E,O overlap rsq latency
  vf2 E = vfma(vfma((vf2){B4, B4}, s, (vf2){B2, B2}), s, (vf2){1.f, 1.f});
  vf2 O = vfma((vf2){B3, B3}, s, (vf2){B1, B1});
  vf2 dd = s * ri;
  vf2 p = vfma(dd, O, E);
  vf2 y;
  y.x = FRCP(p.x);
  y.y = FRCP(p.y);
  vf2 y2 = y * y;
  vf2 y4 = y2 * y2;
  vf2 w = vfma(-y4, ri, ri);  // erf(d/sqrt2)/d
  acc = vfma(qk, w, acc);
}

// One phase: m j-columns starting at jbeg, i-strip at ibeg (512 wide,
// 2 packed i per lane). MCONST=26 -> fully unrolled hot path; MCONST=0 ->
// runtime trip count (fold-crossing blocks only).
template <bool CHECK, int MCONST>
__device__ __forceinline__ void phase_run(const float4* __restrict__ tile,
                                          int m, int jbeg, int ibeg,
                                          const float* __restrict__ q,
                                          const float* __restrict__ r,
                                          int lane, int wid, float& lanesum) {
  const int i0 = ibeg + (wid << 7) + lane;
  const int i1 = i0 + 64;
  const float qi0 = q[i0], qi1 = q[i1];
  vf2 xi = {r[3 * i0], r[3 * i1]};
  vf2 yi = {r[3 * i0 + 1], r[3 * i1 + 1]};
  vf2 zi = {r[3 * i0 + 2], r[3 * i1 + 2]};

  vf2 a0 = {0.f, 0.f}, a1 = {0.f, 0.f};
  if (MCONST > 0) {
#pragma unroll
    for (int k = 0; k < MCONST; k += 2) {
      pair2_body<CHECK>(tile[k], jbeg + k, i0, xi, yi, zi, a0);
      pair2_body<CHECK>(tile[k + 1], jbeg + k + 1, i0, xi, yi, zi, a1);
    }
  } else {
    int k = 0;
    for (; k + 2 <= m; k += 2) {
      pair2_body<CHECK>(tile[k], jbeg + k, i0, xi, yi, zi, a0);
      pair2_body<CHECK>(tile[k + 1], jbeg + k + 1, i0, xi, yi, zi, a1);
    }
    if (k < m) pair2_body<CHECK>(tile[k], jbeg + k, i0, xi, yi, zi, a0);
  }
  vf2 s2 = a0 + a1;
  lanesum = fmaf(qi0, s2.x, fmaf(qi1, s2.y, lanesum));
}

__global__ __launch_bounds__(256) void ewald_fold(
    const float* __restrict__ q, const float* __restrict__ r,
    float* __restrict__ partial, int n) {
  const int tid = threadIdx.x;
  const int lane = tid & 63;
  const int wid = tid >> 6;
  const int s = blockIdx.y;                 // super-strip 0..5
  const int c0 = (int)blockIdx.x * 26;      // column offset in super-strip
  const int nstrips = n >> 9;               // 12
  const int sB = nstrips - 1 - s;           // folded partner strip
  const int LA = n - (s << 9);              // columns in strip s

  int mA = LA - c0;
  mA = mA < 0 ? 0 : (mA > 26 ? 26 : mA);

  __shared__ float4 tile[26];
  float lanesum = 0.f;

  if (mA > 0) {
    const int jbeg = (s << 9) + c0;
    if (tid < mA) {
      int j = jbeg + tid;
      tile[tid] = make_float4(r[3 * j], r[3 * j + 1], r[3 * j + 2], q[j]);
    }
    __syncthreads();
    const bool chk = (c0 < 512);
    const int ibeg = s << 9;
    if (mA == 26) {
      if (chk)
        phase_run<true, 26>(tile, 26, jbeg, ibeg, q, r, lane, wid, lanesum);
      else
        phase_run<false, 26>(tile, 26, jbeg, ibeg, q, r, lane, wid, lanesum);
    } else {
      if (chk)
        phase_run<true, 0>(tile, mA, jbeg, ibeg, q, r, lane, wid, lanesum);
      else
        phase_run<false, 0>(tile, mA, jbeg, ibeg, q, r, lane, wid, lanesum);
    }
    __syncthreads();
  }

  if (mA < 26) {
    int tB0 = c0 - LA;
    if (tB0 < 0) tB0 = 0;
    const int LB = n - (sB << 9);
    int mB = 26 - mA;
    int rem = LB - tB0;
    if (mB > rem) mB = rem;
    if (mB > 0) {
      const int jbeg = (sB << 9) + tB0;
      if (tid < mB) {
        int j = jbeg + tid;
        tile[tid] = make_float4(r[3 * j], r[3 * j + 1], r[3 * j + 2], q[j]);
      }
      __syncthreads();
      const bool chk = (tB0 < 512);
      const int ibeg = sB << 9;
      if (mB == 26) {
        if (chk)
          phase_run<true, 26>(tile, 26, jbeg, ibeg, q, r, lane, wid, lanesum);
        else
          phase_run<false, 26>(tile, 26, jbeg, ibeg, q, r, lane, wid, lanesum);
      } else {
        if (chk)
          phase_run<true, 0>(tile, mB, jbeg, ibeg, q, r, lane, wid, lanesum);
        else
          phase_run<false, 0>(tile, mB, jbeg, ibeg, q, r, lane, wid, lanesum);
      }
    }
  }

  // per-wave reduce; one partial per wave (no cross-wave barrier needed)
  for (int m = 32; m > 0; m >>= 1) lanesum += __shfl_xor(lanesum, m, 64);
  if (lane == 0) {
    const int bid = (int)blockIdx.y * gridDim.x + blockIdx.x;
    partial[bid * 4 + wid] = lanesum;
  }
}

__global__ __launch_bounds__(1024) void reduce_partials(
    const float* __restrict__ partial, float* __restrict__ out, int np,
    float scale) {
  const int tid = threadIdx.x;
  float acc = 0.f;
  for (int idx = tid; idx < np; idx += 1024) acc += partial[idx];
  for (int m = 32; m > 0; m >>= 1) acc += __shfl_xor(acc, m, 64);
  __shared__ float wsum[16];
  const int lane = tid & 63;
  const int wid = tid >> 6;
  if (lane == 0) wsum[wid] = acc;
  __syncthreads();
  if (tid == 0) {
    float ssum = 0.f;
    for (int w = 0; w < 16; ++w) ssum += wsum[w];
    out[0] = ssum * scale;
  }
}

extern "C" void kernel_launch(void* const* d_in, const int* in_sizes, int n_in,
                              void* d_out, int out_size, void* d_ws,
                              size_t ws_size, hipStream_t stream) {
  const float* q = (const float*)d_in[0];  // [N,1] fp32
  const float* r = (const float*)d_in[1];  // [N,3] fp32
  const int n = in_sizes[0];               // 6144
  float* out = (float*)d_out;
  float* partial = (float*)d_ws;

  const int nstrips = n >> 9;              // 12 (512-wide i-strips)
  const int nsupers = nstrips >> 1;        // 6 folded super-strips
  const int superlen = n + 512;            // 6656 j-columns per super
  const int chunks = (superlen + 25) / 26; // 256

  dim3 grid(chunks, nsupers);
  ewald_fold<<<grid, 256, 0, stream>>>(q, r, partial, n);

  const int np = chunks * nsupers * 4;     // one partial per wave
  // 2 (triangle symmetry) * NORM/(2pi)/2 = NORM/(2pi)
  const float scale = (float)(90.0474 / (2.0 * M_PI));
  reduce_partials<<<1, 1024, 0, stream>>>(partial, out, np, scale);
}